// Round 8
// baseline (143.282 us; speedup 1.0000x reference)
//
#include <hip/hip_runtime.h>
#include <math.h>

#define N_HITS 100000
#define NH4 (N_HITS / 4)        // 25000 exact
#define P_PART 300
#define KA_BLOCKS 100
#define PPB 3                   // pids owned per kA block (100*3 = 300)
#define NSPLIT 20
#define PB (P_PART / NSPLIT)    // 15 centers per y-split
#define HPT 8                   // hits per thread in kB
#define TILE (256 * HPT)        // 2048 hits per block-x
#define NBX ((N_HITS + TILE - 1) / TILE)   // 49
#define NBINS 512
#define Q_MIN 0.01f
#define R_THLD 10.0f
#define PT_THLD 0.9f

// ws layout (bytes):
//   [0,     8192): double bins[512][2]        (zeroed by kA blocks 0..3)
//   [8192,  8704): u32 cntb[128]              (NO zeroing needed: cntb[0..100)
//                                              unconditionally written by each
//                                              owning block; kC reads only those.
//                                              Zeroing it raced with the writes!)
//   [8704, 18304): float4 c[600]: c[2p]=x_a[p], c[2p+1]=(|x_a|^2, q_a, 0, 0)
//   [18304,418304): float q_arr[100000]       (sign = mask, |.| = q)

__global__ __launch_bounds__(256) void kA_prep(
        const float* __restrict__ beta,
        const float* __restrict__ x,
        const int* __restrict__ pid,
        const int* __restrict__ recon,
        const float* __restrict__ tp,
        float4* __restrict__ c,
        float4* __restrict__ q4,
        unsigned int* __restrict__ cntb,
        unsigned long long* __restrict__ wsZero) {
    __shared__ unsigned long long bloc[PPB];
    __shared__ int sCnt[4];
    int tid = threadIdx.x, bid = blockIdx.x;
    if (tid < PPB) bloc[tid] = 0ULL;
    // zero ONLY bins (1024 u64). bins is consumed by kB/kC (stream-ordered),
    // so cross-block timing is irrelevant. Do NOT touch cntb here (race!).
    {
        int g = bid * 256 + tid;
        if (g < 1024) wsZero[g] = 0ULL;
    }

    // ---- phase 1: q-precompute + mask count on this block's 1000-hit slice ----
    const float4* b4 = (const float4*)beta;
    const int4*   r4 = (const int4*)recon;
    const float4* t4 = (const float4*)tp;
    int cnt = 0;
    if (tid < 250) {                       // 250 float4s per block, 1 iter/thread
        int j = bid * 250 + tid;
        float4 b = b4[j];
        int4   rc = r4[j];
        float4 t = t4[j];
        float4 qo;
        {
            float a = atanhf(b.x); float qv = a * a + Q_MIN;
            bool mk = (rc.x > 0) && (t.x > PT_THLD); cnt += mk; qo.x = mk ? -qv : qv;
        }
        {
            float a = atanhf(b.y); float qv = a * a + Q_MIN;
            bool mk = (rc.y > 0) && (t.y > PT_THLD); cnt += mk; qo.y = mk ? -qv : qv;
        }
        {
            float a = atanhf(b.z); float qv = a * a + Q_MIN;
            bool mk = (rc.z > 0) && (t.z > PT_THLD); cnt += mk; qo.z = mk ? -qv : qv;
        }
        {
            float a = atanhf(b.w); float qv = a * a + Q_MIN;
            bool mk = (rc.w > 0) && (t.w > PT_THLD); cnt += mk; qo.w = mk ? -qv : qv;
        }
        q4[j] = qo;
    }
    #pragma unroll
    for (int off = 32; off > 0; off >>= 1) cnt += __shfl_down(cnt, off, 64);
    if ((tid & 63) == 0) sCnt[tid >> 6] = cnt;
    __syncthreads();                        // bloc init + sCnt visible
    if (tid == 0) cntb[bid] = (unsigned)(sCnt[0] + sCnt[1] + sCnt[2] + sCnt[3]);

    // ---- phase 2: argmax-beta for OWNED pids over the whole hit array ----
    // q monotonic in beta -> argmax beta == argmax q. beta>0 -> float bits
    // order as values; low word ~i picks smallest i on ties (jnp.argmax).
    int lo = 1 + PPB * bid;                 // owned pids [lo, lo+PPB)
    const int4* p4 = (const int4*)pid;
    for (int j = tid; j < NH4; j += 256) {
        int4 pv = p4[j];
        int base = 4 * j;
        #pragma unroll
        for (int e = 0; e < 4; ++e) {
            int p = (&pv.x)[e];
            unsigned u = (unsigned)(p - lo);
            if (u < PPB) {                  // rare (~1%): exec-masked path
                int i = base + e;
                unsigned long long pack =
                    ((unsigned long long)__float_as_uint(beta[i]) << 32) |
                    (unsigned long long)(~(unsigned)i);
                atomicMax(&bloc[u], pack);  // LDS atomic, bank-parallel
            }
        }
    }
    __syncthreads();

    // ---- phase 3: write this block's centers directly (no global atomics) ----
    if (tid < PPB) {
        unsigned long long b = bloc[tid];
        unsigned idx = (b == 0ULL) ? 0u : ~(unsigned)(b & 0xffffffffULL);
        float a = atanhf(beta[idx]);
        float4 xa = ((const float4*)x)[idx];
        float na = xa.x * xa.x + xa.y * xa.y + xa.z * xa.z + xa.w * xa.w;
        int pd = PPB * bid + tid;           // pid-1
        c[2 * pd] = xa;
        c[2 * pd + 1] = make_float4(na, a * a + Q_MIN, 0.f, 0.f);
    }
}

__global__ __launch_bounds__(256, 4) void kB_main(
        const float* __restrict__ x,
        const int* __restrict__ pid,
        const float* __restrict__ q_arr,
        const float4* __restrict__ c,
        double* __restrict__ bins) {
    __shared__ float4 xa_s[PB];
    __shared__ float2 nq_s[PB];             // (|x_a|^2, q_a)
    int p0 = blockIdx.y * PB;
    if (threadIdx.x < PB) {
        float4 r1 = c[2 * (p0 + threadIdx.x) + 1];
        xa_s[threadIdx.x] = c[2 * (p0 + threadIdx.x)];
        nq_s[threadIdx.x] = make_float2(r1.x, r1.y);
    }
    __syncthreads();

    int base = blockIdx.x * TILE + threadIdx.x;
    float4 m2[HPT];                         // -2 * x_i
    float  sx[HPT];                         // |x_i|^2 + 1e-8
    float  q[HPT], aq[HPT], racc[HPT];
    int    pm1[HPT];
    #pragma unroll
    for (int h = 0; h < HPT; ++h) {
        int i = base + h * 256;
        bool valid = (i < N_HITS);
        int ii = valid ? i : 0;
        float4 xi = ((const float4*)x)[ii];
        m2[h] = make_float4(-2.f * xi.x, -2.f * xi.y, -2.f * xi.z, -2.f * xi.w);
        sx[h] = xi.x * xi.x + xi.y * xi.y + xi.z * xi.z + xi.w * xi.w + 1e-8f;
        float qraw = q_arr[ii];
        float qv = fabsf(qraw);
        q[h]  = valid ? qv : 0.f;           // q=0 nullifies OOB lanes
        aq[h] = (valid && qraw < 0.f) ? qv : 0.f;   // sign bit == mask
        pm1[h] = valid ? (pid[ii] - 1) : -1;
        racc[h] = 0.f;
    }

    #pragma unroll 3
    for (int p = 0; p < PB; ++p) {
        float4 xa = xa_s[p];                // uniform -> LDS broadcast, 0 conflicts
        float2 nq = nq_s[p];
        #pragma unroll
        for (int h = 0; h < HPT; ++h) {
            float n = sx[h] + nq.x;
            n = fmaf(m2[h].x, xa.x, n);
            n = fmaf(m2[h].y, xa.y, n);
            n = fmaf(m2[h].z, xa.z, n);
            n = fmaf(m2[h].w, xa.w, n);
            float s = __builtin_amdgcn_sqrtf(fmaxf(n, 0.f));   // raw v_sqrt_f32
            racc[h] = fmaf(fmaxf(R_THLD - s, 0.f), nq.y, racc[h]);
        }
    }

    float att = 0.f, rep = 0.f;
    #pragma unroll
    for (int h = 0; h < HPT; ++h) {
        int lp = pm1[h] - p0;
        if (lp >= 0 && lp < PB) {           // this split owns the own-pid term
            float4 xa = xa_s[lp];
            float2 nq = nq_s[lp];
            // IDENTICAL op sequence as the loop -> exact cancellation
            float n = sx[h] + nq.x;
            n = fmaf(m2[h].x, xa.x, n);
            n = fmaf(m2[h].y, xa.y, n);
            n = fmaf(m2[h].z, xa.z, n);
            n = fmaf(m2[h].w, xa.w, n);
            float s = __builtin_amdgcn_sqrtf(fmaxf(n, 0.f));
            racc[h] -= fmaxf(R_THLD - s, 0.f) * nq.y;
            att += aq[h] * (n - 1e-8f) * nq.y;   // attractive: nsq without eps
        }
        rep += q[h] * racc[h];
    }

    // wave reduce -> block reduce -> spread-bin fire-and-forget f64 atomics
    #pragma unroll
    for (int off = 32; off > 0; off >>= 1) {
        att += __shfl_down(att, off, 64);
        rep += __shfl_down(rep, off, 64);
    }
    __shared__ float sA[4], sR[4];
    int wid = threadIdx.x >> 6;
    if ((threadIdx.x & 63) == 0) { sA[wid] = att; sR[wid] = rep; }
    __syncthreads();
    if (threadIdx.x == 0) {
        float A = sA[0] + sA[1] + sA[2] + sA[3];
        float R = sR[0] + sR[1] + sR[2] + sR[3];
        int bin = (int)((blockIdx.y * gridDim.x + blockIdx.x) & (NBINS - 1));
        atomicAdd(&bins[2 * bin], (double)A);
        atomicAdd(&bins[2 * bin + 1], (double)R);
    }
}

__global__ __launch_bounds__(256) void kC_fin(
        const double* __restrict__ bins,
        const unsigned int* __restrict__ cntb,
        float* __restrict__ out) {
    double a = 0.0, r = 0.0;
    long long cnt = 0;
    for (int t = threadIdx.x; t < NBINS; t += 256) {
        a += bins[2 * t];
        r += bins[2 * t + 1];
    }
    if (threadIdx.x < KA_BLOCKS) cnt = (long long)cntb[threadIdx.x];
    #pragma unroll
    for (int off = 32; off > 0; off >>= 1) {
        a += __shfl_down(a, off, 64);
        r += __shfl_down(r, off, 64);
        cnt += __shfl_down(cnt, off, 64);
    }
    __shared__ double dA[4], dR[4];
    __shared__ long long dC[4];
    int wid = threadIdx.x >> 6;
    if ((threadIdx.x & 63) == 0) { dA[wid] = a; dR[wid] = r; dC[wid] = cnt; }
    __syncthreads();
    if (threadIdx.x == 0) {
        a = dA[0] + dA[1] + dA[2] + dA[3];
        r = dR[0] + dR[1] + dR[2] + dR[3];
        cnt = dC[0] + dC[1] + dC[2] + dC[3];
        out[0] = (float)(a / (double)cnt);
        out[1] = (float)(r / (double)N_HITS);
    }
}

extern "C" void kernel_launch(void* const* d_in, const int* in_sizes, int n_in,
                              void* d_out, int out_size, void* d_ws, size_t ws_size,
                              hipStream_t stream) {
    const float* beta  = (const float*)d_in[0];
    const float* x     = (const float*)d_in[1];
    const int*   pid   = (const int*)d_in[2];
    const int*   recon = (const int*)d_in[3];
    const float* tp    = (const float*)d_in[4];
    float* out = (float*)d_out;

    char* ws = (char*)d_ws;
    double*             bins  = (double*)(ws);
    unsigned int*       cntb  = (unsigned int*)(ws + 8192);
    float4*             c     = (float4*)(ws + 8704);
    float4*             q4    = (float4*)(ws + 18304);
    float*              q_arr = (float*)(ws + 18304);
    unsigned long long* wsZ   = (unsigned long long*)(ws);

    kA_prep<<<KA_BLOCKS, 256, 0, stream>>>(beta, x, pid, recon, tp,
                                           c, q4, cntb, wsZ);
    kB_main<<<dim3(NBX, NSPLIT), 256, 0, stream>>>(x, pid, q_arr, c, bins);
    kC_fin<<<1, 256, 0, stream>>>(bins, cntb, out);
}

// Round 9
// 94.830 us; speedup vs baseline: 1.5109x; 1.5109x over previous
//
#include <hip/hip_runtime.h>
#include <math.h>

#define N_HITS 100000
#define NH4 (N_HITS / 4)        // 25000 exact
#define P_PART 300
#define KA_BLOCKS 40
#define CHUNK4 (NH4 / KA_BLOCKS)  // 625 float4s (2500 hits) per kA block
#define NSPLIT 20
#define PB (P_PART / NSPLIT)    // 15 centers per y-split
#define HPT 8                   // hits per thread in kB
#define TILE (256 * HPT)        // 2048 hits per block-x
#define NBX ((N_HITS + TILE - 1) / TILE)   // 49
#define NBINS 512
#define Q_MIN 0.01f
#define R_THLD 10.0f
#define PT_THLD 0.9f

// ws layout (bytes):
//   [0,     8192): double bins[512][2]     (memset)
//   [8192, 10592): u64 best[300]           (memset)  packed (beta_bits<<32)|~i
//   [10592,10596): u32 doneA               (memset)
//   [10624,11136): u32 cntb[128]           (NOT memset: cntb[0..40) written
//                                           unconditionally by owner blocks;
//                                           zeroing it would race - round 7 bug)
//   [11136,20736): float4 c[600]: c[2p]=x_a[p], c[2p+1]=(|x_a|^2, q_a, 0, 0)
//   [20736,420736): float q_arr[100000]    (sign = mask, |.| = q)

__global__ __launch_bounds__(256) void kA_prep(
        const float* __restrict__ beta,
        const float* __restrict__ x,
        const int* __restrict__ pid,
        const int* __restrict__ recon,
        const float* __restrict__ tp,
        unsigned long long* __restrict__ best,
        unsigned int* __restrict__ doneA,
        unsigned int* __restrict__ cntb,
        float4* __restrict__ c,
        float4* __restrict__ q4) {
    __shared__ unsigned long long bloc[P_PART];
    __shared__ int sCnt[4];
    __shared__ int isLast;
    int tid = threadIdx.x, bid = blockIdx.x;
    for (int s = tid; s < P_PART; s += 256) bloc[s] = 0ULL;
    __syncthreads();

    // ---- single pass over this block's 2500-hit slice:
    //      q precompute + mask count + LDS argmax(beta) per pid ----
    const float4* b4 = (const float4*)beta;
    const int4*   p4 = (const int4*)pid;
    const int4*   r4 = (const int4*)recon;
    const float4* t4 = (const float4*)tp;
    int cnt = 0;
    int j0 = bid * CHUNK4;
    for (int j = j0 + tid; j < j0 + CHUNK4; j += 256) {
        float4 b = b4[j];
        int4   pv = p4[j];
        int4   rc = r4[j];
        float4 t = t4[j];
        float4 qo;
        #pragma unroll
        for (int e = 0; e < 4; ++e) {
            float bv = (&b.x)[e];
            float a = atanhf(bv);
            float qv = a * a + Q_MIN;
            bool mk = ((&rc.x)[e] > 0) && ((&t.x)[e] > PT_THLD);
            cnt += mk;
            (&qo.x)[e] = mk ? -qv : qv;
            int p = (&pv.x)[e];
            if (p > 0) {
                // q monotonic in beta -> argmax beta == argmax q. beta>0 ->
                // float bits order as values; ~i picks smallest i on ties
                // (jnp.argmax first-occurrence semantics).
                int i = 4 * j + e;
                unsigned long long pack =
                    ((unsigned long long)__float_as_uint(bv) << 32) |
                    (unsigned long long)(~(unsigned)i);
                atomicMax(&bloc[p - 1], pack);   // LDS atomic, bank-parallel
            }
        }
        q4[j] = qo;
    }
    __syncthreads();                          // LDS table complete

    // ---- flush block table -> global best (fire-and-forget, 300/block) ----
    for (int s = tid; s < P_PART; s += 256) {
        unsigned long long v = bloc[s];
        if (v) atomicMax(&best[s], v);
    }
    // mask count: wave reduce -> block reduce -> plain store (disjoint slot)
    #pragma unroll
    for (int off = 32; off > 0; off >>= 1) cnt += __shfl_down(cnt, off, 64);
    if ((tid & 63) == 0) sCnt[tid >> 6] = cnt;
    __threadfence();                          // order flush atomics
    __syncthreads();                          // drains vmcnt block-wide
    if (tid == 0) {
        cntb[bid] = (unsigned)(sCnt[0] + sCnt[1] + sCnt[2] + sCnt[3]);
        unsigned int old = atomicAdd(doneA, 1u);
        isLast = (old == (unsigned int)(KA_BLOCKS - 1)) ? 1 : 0;
    }
    __syncthreads();
    if (isLast) {                             // last block gathers centers
        for (int s = tid; s < P_PART; s += 256) {
            unsigned long long b = atomicOr(&best[s], 0ULL);  // coherent read
            unsigned idx = (b == 0ULL) ? 0u : ~(unsigned)(b & 0xffffffffULL);
            float a = atanhf(beta[idx]);
            float4 xa = ((const float4*)x)[idx];
            float na = xa.x * xa.x + xa.y * xa.y + xa.z * xa.z + xa.w * xa.w;
            c[2 * s] = xa;
            c[2 * s + 1] = make_float4(na, a * a + Q_MIN, 0.f, 0.f);
        }
    }
}

__global__ __launch_bounds__(256, 4) void kB_main(
        const float* __restrict__ x,
        const int* __restrict__ pid,
        const float* __restrict__ q_arr,
        const float4* __restrict__ c,
        double* __restrict__ bins) {
    __shared__ float4 xa_s[PB];
    __shared__ float2 nq_s[PB];             // (|x_a|^2, q_a)
    int p0 = blockIdx.y * PB;
    if (threadIdx.x < PB) {
        float4 r1 = c[2 * (p0 + threadIdx.x) + 1];
        xa_s[threadIdx.x] = c[2 * (p0 + threadIdx.x)];
        nq_s[threadIdx.x] = make_float2(r1.x, r1.y);
    }
    __syncthreads();

    int base = blockIdx.x * TILE + threadIdx.x;
    float4 m2[HPT];                         // -2 * x_i
    float  sx[HPT];                         // |x_i|^2 + 1e-8
    float  q[HPT], aq[HPT], racc[HPT];
    int    pm1[HPT];
    #pragma unroll
    for (int h = 0; h < HPT; ++h) {
        int i = base + h * 256;
        bool valid = (i < N_HITS);
        int ii = valid ? i : 0;
        float4 xi = ((const float4*)x)[ii];
        m2[h] = make_float4(-2.f * xi.x, -2.f * xi.y, -2.f * xi.z, -2.f * xi.w);
        sx[h] = xi.x * xi.x + xi.y * xi.y + xi.z * xi.z + xi.w * xi.w + 1e-8f;
        float qraw = q_arr[ii];
        float qv = fabsf(qraw);
        q[h]  = valid ? qv : 0.f;           // q=0 nullifies OOB lanes
        aq[h] = (valid && qraw < 0.f) ? qv : 0.f;   // sign bit == mask
        pm1[h] = valid ? (pid[ii] - 1) : -1;
        racc[h] = 0.f;
    }

    #pragma unroll 3
    for (int p = 0; p < PB; ++p) {
        float4 xa = xa_s[p];                // uniform -> LDS broadcast, 0 conflicts
        float2 nq = nq_s[p];
        #pragma unroll
        for (int h = 0; h < HPT; ++h) {
            float n = sx[h] + nq.x;
            n = fmaf(m2[h].x, xa.x, n);
            n = fmaf(m2[h].y, xa.y, n);
            n = fmaf(m2[h].z, xa.z, n);
            n = fmaf(m2[h].w, xa.w, n);
            float s = __builtin_amdgcn_sqrtf(fmaxf(n, 0.f));   // raw v_sqrt_f32
            racc[h] = fmaf(fmaxf(R_THLD - s, 0.f), nq.y, racc[h]);
        }
    }

    float att = 0.f, rep = 0.f;
    #pragma unroll
    for (int h = 0; h < HPT; ++h) {
        int lp = pm1[h] - p0;
        if (lp >= 0 && lp < PB) {           // this split owns the own-pid term
            float4 xa = xa_s[lp];
            float2 nq = nq_s[lp];
            // IDENTICAL op sequence as the loop -> exact cancellation
            float n = sx[h] + nq.x;
            n = fmaf(m2[h].x, xa.x, n);
            n = fmaf(m2[h].y, xa.y, n);
            n = fmaf(m2[h].z, xa.z, n);
            n = fmaf(m2[h].w, xa.w, n);
            float s = __builtin_amdgcn_sqrtf(fmaxf(n, 0.f));
            racc[h] -= fmaxf(R_THLD - s, 0.f) * nq.y;
            att += aq[h] * (n - 1e-8f) * nq.y;   // attractive: nsq without eps
        }
        rep += q[h] * racc[h];
    }

    // wave reduce -> block reduce -> spread-bin fire-and-forget f64 atomics
    #pragma unroll
    for (int off = 32; off > 0; off >>= 1) {
        att += __shfl_down(att, off, 64);
        rep += __shfl_down(rep, off, 64);
    }
    __shared__ float sA[4], sR[4];
    int wid = threadIdx.x >> 6;
    if ((threadIdx.x & 63) == 0) { sA[wid] = att; sR[wid] = rep; }
    __syncthreads();
    if (threadIdx.x == 0) {
        float A = sA[0] + sA[1] + sA[2] + sA[3];
        float R = sR[0] + sR[1] + sR[2] + sR[3];
        int bin = (int)((blockIdx.y * gridDim.x + blockIdx.x) & (NBINS - 1));
        atomicAdd(&bins[2 * bin], (double)A);
        atomicAdd(&bins[2 * bin + 1], (double)R);
    }
}

__global__ __launch_bounds__(256) void kC_fin(
        const double* __restrict__ bins,
        const unsigned int* __restrict__ cntb,
        float* __restrict__ out) {
    double a = 0.0, r = 0.0;
    long long cnt = 0;
    for (int t = threadIdx.x; t < NBINS; t += 256) {
        a += bins[2 * t];
        r += bins[2 * t + 1];
    }
    if (threadIdx.x < KA_BLOCKS) cnt = (long long)cntb[threadIdx.x];
    #pragma unroll
    for (int off = 32; off > 0; off >>= 1) {
        a += __shfl_down(a, off, 64);
        r += __shfl_down(r, off, 64);
        cnt += __shfl_down(cnt, off, 64);
    }
    __shared__ double dA[4], dR[4];
    __shared__ long long dC[4];
    int wid = threadIdx.x >> 6;
    if ((threadIdx.x & 63) == 0) { dA[wid] = a; dR[wid] = r; dC[wid] = cnt; }
    __syncthreads();
    if (threadIdx.x == 0) {
        a = dA[0] + dA[1] + dA[2] + dA[3];
        r = dR[0] + dR[1] + dR[2] + dR[3];
        cnt = dC[0] + dC[1] + dC[2] + dC[3];
        out[0] = (float)(a / (double)cnt);
        out[1] = (float)(r / (double)N_HITS);
    }
}

extern "C" void kernel_launch(void* const* d_in, const int* in_sizes, int n_in,
                              void* d_out, int out_size, void* d_ws, size_t ws_size,
                              hipStream_t stream) {
    const float* beta  = (const float*)d_in[0];
    const float* x     = (const float*)d_in[1];
    const int*   pid   = (const int*)d_in[2];
    const int*   recon = (const int*)d_in[3];
    const float* tp    = (const float*)d_in[4];
    float* out = (float*)d_out;

    char* ws = (char*)d_ws;
    double*             bins  = (double*)(ws);
    unsigned long long* best  = (unsigned long long*)(ws + 8192);
    unsigned int*       doneA = (unsigned int*)(ws + 10592);
    unsigned int*       cntb  = (unsigned int*)(ws + 10624);
    float4*             c     = (float4*)(ws + 11136);
    float4*             q4    = (float4*)(ws + 20736);
    float*              q_arr = (float*)(ws + 20736);

    // zero bins + best + doneA only (cntb must NOT be zeroed - see layout note)
    hipMemsetAsync(d_ws, 0, 10596, stream);

    kA_prep<<<KA_BLOCKS, 256, 0, stream>>>(beta, x, pid, recon, tp,
                                           best, doneA, cntb, c, q4);
    kB_main<<<dim3(NBX, NSPLIT), 256, 0, stream>>>(x, pid, q_arr, c, bins);
    kC_fin<<<1, 256, 0, stream>>>(bins, cntb, out);
}